// Round 2
// baseline (2085.810 us; speedup 1.0000x reference)
//
#include <hip/hip_runtime.h>

#define FEAT 512
#define NCLS 20
#define NSUP 200
#define NQ   200000
#define HID  256
#define RB   32     // query rows per block batch in pass1
#define WST  36     // padded stride (floats) for softmax-weight LDS rows

// ---- workspace layout (float offsets) ----
#define ACC_O   0        // 3*20*512 soft^T @ qn accumulators
#define WSUM_O  30720    // 3*20
#define CNT_O   30780    // 20
#define CSUM_O  30800    // 20*512 class sums of LN'd support
#define ZERO_N  41040    // everything before here is zeroed each launch
#define PROT_O  41040    // 20*512 LN'd prototypes
#define PSQ_O   51280    // 20
#define H1_O    51300    // 20*256 proto-MLP hidden
#define PRAW_O  56420    // 20*512 raw prototypes
#define HBUF_O  66660    // 20*512 refine hidden
#define REF_O   76900    // 20*512 refined
#define RFLN_O  87140    // 20*512 LN'd refined
#define RSQ_O   97380    // 20

template<int CTRL>
static __device__ __forceinline__ float dpp_add(float v) {
  int r = __builtin_amdgcn_update_dpp(0, __float_as_int(v), CTRL, 0xF, 0xF, true);
  return v + __int_as_float(r);
}

// butterfly sum over all 64 lanes, result in every lane
static __device__ __forceinline__ float allsum(float v) {
  v = dpp_add<0xB1>(v);    // quad_perm [1,0,3,2]  : xor 1
  v = dpp_add<0x4E>(v);    // quad_perm [2,3,0,1]  : xor 2
  v = dpp_add<0x141>(v);   // row_half_mirror      : combine quads within 8
  v = dpp_add<0x140>(v);   // row_mirror           : combine 8s within 16
  v += __int_as_float(__builtin_amdgcn_ds_swizzle(__float_as_int(v), 0x401F)); // xor 16
  v += __shfl_xor(v, 32, 64);                                                  // xor 32
  return v;
}

static __device__ __forceinline__ float dot8(const float4 a0, const float4 a1,
                                             const float4 b0, const float4 b1) {
  float t = a0.x * b0.x;
  t = fmaf(a0.y, b0.y, t); t = fmaf(a0.z, b0.z, t); t = fmaf(a0.w, b0.w, t);
  t = fmaf(a1.x, b1.x, t); t = fmaf(a1.y, b1.y, t); t = fmaf(a1.z, b1.z, t);
  t = fmaf(a1.w, b1.w, t);
  return t;
}

// LayerNorm of one 512-wide row held wave-wide: lane i owns cols [4i,4i+4) and [256+4i, 256+4i+4)
static __device__ __forceinline__ void ln_row(const float4 x0, const float4 x1,
    const float4 g0, const float4 g1, const float4 b0, const float4 b1,
    float4& n0, float4& n1, float& qsq)
{
  float s8 = ((x0.x + x0.y) + (x0.z + x0.w)) + ((x1.x + x1.y) + (x1.z + x1.w));
  float q8 = x0.x * x0.x;
  q8 = fmaf(x0.y, x0.y, q8); q8 = fmaf(x0.z, x0.z, q8); q8 = fmaf(x0.w, x0.w, q8);
  q8 = fmaf(x1.x, x1.x, q8); q8 = fmaf(x1.y, x1.y, q8); q8 = fmaf(x1.z, x1.z, q8);
  q8 = fmaf(x1.w, x1.w, q8);
  float S = allsum(s8);
  float Q = allsum(q8);
  float m = S * (1.0f / FEAT);
  float var = fmaxf(Q * (1.0f / FEAT) - m * m, 0.0f);
  float rs = rsqrtf(var + 1e-5f);
  n0.x = fmaf((x0.x - m) * rs, g0.x, b0.x);
  n0.y = fmaf((x0.y - m) * rs, g0.y, b0.y);
  n0.z = fmaf((x0.z - m) * rs, g0.z, b0.z);
  n0.w = fmaf((x0.w - m) * rs, g0.w, b0.w);
  n1.x = fmaf((x1.x - m) * rs, g1.x, b1.x);
  n1.y = fmaf((x1.y - m) * rs, g1.y, b1.y);
  n1.z = fmaf((x1.z - m) * rs, g1.z, b1.z);
  n1.w = fmaf((x1.w - m) * rs, g1.w, b1.w);
  qsq = allsum(dot8(n0, n1, n0, n1));
}

// ---------------- setup: LN support rows + per-class sums ----------------
__global__ __launch_bounds__(512) void k_setup_a(
    const float* __restrict__ sup, const int* __restrict__ lab,
    const float* __restrict__ gp, const float* __restrict__ bp, float* __restrict__ ws)
{
  const int lane = threadIdx.x & 63;
  const int wv = threadIdx.x >> 6;
  const int row = blockIdx.x * 8 + wv;
  if (row >= NSUP) return;
  const float4 g0 = ((const float4*)gp)[lane];
  const float4 g1 = ((const float4*)gp)[64 + lane];
  const float4 b0 = ((const float4*)bp)[lane];
  const float4 b1 = ((const float4*)bp)[64 + lane];
  const float4* r4 = (const float4*)(sup + (size_t)row * FEAT);
  float4 x0 = r4[lane], x1 = r4[64 + lane];
  float4 n0, n1; float qs;
  ln_row(x0, x1, g0, g1, b0, b1, n0, n1, qs);
  const int c = lab[row];
  float* dst = ws + CSUM_O + c * FEAT + 4 * lane;
  atomicAdd(dst + 0, n0.x); atomicAdd(dst + 1, n0.y);
  atomicAdd(dst + 2, n0.z); atomicAdd(dst + 3, n0.w);
  float* dst2 = dst + 256;
  atomicAdd(dst2 + 0, n1.x); atomicAdd(dst2 + 1, n1.y);
  atomicAdd(dst2 + 2, n1.z); atomicAdd(dst2 + 3, n1.w);
  if (lane == 0) atomicAdd(ws + CNT_O + c, 1.0f);
}

// ---------------- proto MLP layer 1 (relu(cmean@W1+b1)) ----------------
__global__ __launch_bounds__(256) void k_setup_b(
    const float* __restrict__ w1, const float* __restrict__ b1v, float* __restrict__ ws)
{
  const int k = blockIdx.x;
  const int o = threadIdx.x;
  const float rw = 1.0f / fmaxf(ws[CNT_O + k], 1.0f);
  const float* cs = ws + CSUM_O + k * FEAT;
  float a0 = 0, a1 = 0, a2 = 0, a3 = 0;
  for (int j = 0; j < FEAT; j += 4) {
    a0 = fmaf(cs[j + 0], w1[(j + 0) * HID + o], a0);
    a1 = fmaf(cs[j + 1], w1[(j + 1) * HID + o], a1);
    a2 = fmaf(cs[j + 2], w1[(j + 2) * HID + o], a2);
    a3 = fmaf(cs[j + 3], w1[(j + 3) * HID + o], a3);
  }
  float acc = fmaf((a0 + a1) + (a2 + a3), rw, b1v[o]);
  ws[H1_O + k * HID + o] = fmaxf(acc, 0.0f);
}

// ---------------- proto MLP layer 2 ----------------
__global__ __launch_bounds__(512) void k_setup_c(
    const float* __restrict__ w2, const float* __restrict__ b2v, float* __restrict__ ws)
{
  const int k = blockIdx.x;
  const int o = threadIdx.x;
  const float* h = ws + H1_O + k * HID;
  float a0 = 0, a1 = 0, a2 = 0, a3 = 0;
  for (int j = 0; j < HID; j += 4) {
    a0 = fmaf(h[j + 0], w2[(j + 0) * FEAT + o], a0);
    a1 = fmaf(h[j + 1], w2[(j + 1) * FEAT + o], a1);
    a2 = fmaf(h[j + 2], w2[(j + 2) * FEAT + o], a2);
    a3 = fmaf(h[j + 3], w2[(j + 3) * FEAT + o], a3);
  }
  ws[PRAW_O + k * FEAT + o] = ((a0 + a1) + (a2 + a3)) + b2v[o];
}

// ---------------- LN of the 20 rows at src_o -> dst_o (+optional copy, +sum of squares) ----------------
__global__ __launch_bounds__(512) void k_ln20(
    const float* __restrict__ gp, const float* __restrict__ bp, float* __restrict__ ws,
    int src_o, int dst_o, int dst2_o, int sq_o)
{
  const int lane = threadIdx.x & 63;
  const int wv = threadIdx.x >> 6;
  const float4 g0 = ((const float4*)gp)[lane];
  const float4 g1 = ((const float4*)gp)[64 + lane];
  const float4 b0 = ((const float4*)bp)[lane];
  const float4 b1 = ((const float4*)bp)[64 + lane];
  for (int k = wv; k < NCLS; k += 8) {
    const float4* r4 = (const float4*)(ws + src_o + k * FEAT);
    float4 x0 = r4[lane], x1 = r4[64 + lane];
    float4 n0, n1; float qs;
    ln_row(x0, x1, g0, g1, b0, b1, n0, n1, qs);
    float4* d4 = (float4*)(ws + dst_o + k * FEAT);
    d4[lane] = n0; d4[64 + lane] = n1;
    if (dst2_o >= 0) {
      float4* e4 = (float4*)(ws + dst2_o + k * FEAT);
      e4[lane] = n0; e4[64 + lane] = n1;
    }
    if (lane == 0) ws[sq_o + k] = qs;
  }
}

// ---------------- pass 1: fused LN + dist + 3 softmaxes + soft^T@qn accumulation ----------------
__global__ __launch_bounds__(512, 2) void k_pass1(
    const float* __restrict__ qry, const float* __restrict__ gp, const float* __restrict__ bp,
    float* __restrict__ ws)
{
  __shared__ __align__(16) float pro_s[NCLS * FEAT];   // 40 KB
  __shared__ __align__(16) float qn_s[RB * FEAT];      // 64 KB
  __shared__ __align__(16) float w_s[60 * WST];        // 8.6 KB

  const int tid = threadIdx.x;
  const int lane = tid & 63;
  const int wv = tid >> 6;

  for (int i = tid; i < NCLS * FEAT / 4; i += 512)
    ((float4*)pro_s)[i] = ((const float4*)(ws + PROT_O))[i];

  const float4 g0 = ((const float4*)gp)[lane];
  const float4 g1 = ((const float4*)gp)[64 + lane];
  const float4 b0 = ((const float4*)bp)[lane];
  const float4 b1 = ((const float4*)bp)[64 + lane];

  float psq[NCLS];
#pragma unroll
  for (int k = 0; k < NCLS; ++k) psq[k] = ws[PSQ_O + k];

  const int myk = lane % 20;
  const int myt = lane / 20;
  const bool sact = lane < 60;
  const float invt = (myt == 0) ? 1.0f : ((myt == 1) ? 0.5f : (1.0f / 3.0f));
  float wloc = 0.0f;

  const int tg = tid >> 7;     // tk group: owns tk = tg*15 .. tg*15+14
  const int jg = tid & 127;    // owns cols 4*jg .. 4*jg+3
  float av[15][4];
#pragma unroll
  for (int a = 0; a < 15; ++a)
#pragma unroll
    for (int c = 0; c < 4; ++c) av[a][c] = 0.0f;

  auto softmax_row = [&](float qs, const float (&d)[20], int lr) {
    float dd[20];
#pragma unroll
    for (int k = 0; k < 20; ++k) dd[k] = fmaxf(fmaf(-2.0f, d[k], qs + psq[k]), 0.0f);
    float mm[10];
#pragma unroll
    for (int k = 0; k < 10; ++k) mm[k] = fminf(dd[k], dd[k + 10]);
#pragma unroll
    for (int k = 0; k < 5; ++k) mm[k] = fminf(mm[k], mm[k + 5]);
    mm[0] = fminf(mm[0], mm[3]);
    mm[1] = fminf(mm[1], mm[4]);
    mm[0] = fminf(mm[0], mm[2]);
    float dmin = fminf(mm[0], mm[1]);
    float dk = dd[0];
#pragma unroll
    for (int k = 1; k < 20; ++k) dk = (myk == k) ? dd[k] : dk;
    float e = __expf((dmin - dk) * invt);
    e = sact ? e : 0.0f;
    float s = e;
    { float t = __shfl_down(s, 16, 64); s += (myk + 16 < 20) ? t : 0.0f; }
    { float t = __shfl_down(s, 8, 64);  s += (myk + 8  < 20) ? t : 0.0f; }
    { float t = __shfl_down(s, 4, 64);  s += (myk + 4  < 20) ? t : 0.0f; }
    { float t = __shfl_down(s, 2, 64);  s += (myk + 2  < 20) ? t : 0.0f; }
    { float t = __shfl_down(s, 1, 64);  s += (myk + 1  < 20) ? t : 0.0f; }
    float denom = __shfl(s, myt * 20, 64);   // group leader has full sum (>=1, safe)
    float wgt = e * __builtin_amdgcn_rcpf(denom);
    if (sact) { w_s[lane * WST + lr] = wgt; wloc += wgt; }
  };

  __syncthreads();

  for (int bt = blockIdx.x; bt < NQ / RB; bt += gridDim.x) {
    const int lr0 = wv * 4;                           // this wave's 4 local rows
    const float* qb = qry + (size_t)(bt * RB + lr0) * FEAT;
    float4 x[4][2];
#pragma unroll
    for (int r = 0; r < 4; ++r) {
      x[r][0] = ((const float4*)(qb + r * FEAT))[lane];
      x[r][1] = ((const float4*)(qb + r * FEAT))[64 + lane];
    }
#pragma unroll
    for (int pr = 0; pr < 2; ++pr) {
      float4 na0, na1, nb0, nb1;
      float qsa, qsb;
      ln_row(x[2 * pr][0], x[2 * pr][1], g0, g1, b0, b1, na0, na1, qsa);
      ln_row(x[2 * pr + 1][0], x[2 * pr + 1][1], g0, g1, b0, b1, nb0, nb1, qsb);
      float4* qa4 = (float4*)(qn_s + (lr0 + 2 * pr) * FEAT);
      qa4[lane] = na0; qa4[64 + lane] = na1;
      float4* qb4 = (float4*)(qn_s + (lr0 + 2 * pr + 1) * FEAT);
      qb4[lane] = nb0; qb4[64 + lane] = nb1;
      float da[20], db[20];
#pragma unroll
      for (int k = 0; k < 20; ++k) {
        const float4 p0 = *(const float4*)(pro_s + k * FEAT + 4 * lane);
        const float4 p1 = *(const float4*)(pro_s + k * FEAT + 256 + 4 * lane);
        da[k] = dot8(na0, na1, p0, p1);
        db[k] = dot8(nb0, nb1, p0, p1);
      }
#pragma unroll
      for (int k = 0; k < 20; ++k) { da[k] = allsum(da[k]); db[k] = allsum(db[k]); }
      softmax_row(qsa, da, lr0 + 2 * pr);
      softmax_row(qsb, db, lr0 + 2 * pr + 1);
    }
    __syncthreads();
    // phase B: rank-32 update, thread owns (15 tk) x (4 cols) in registers
    for (int r4 = 0; r4 < RB; r4 += 4) {
      const float4 q0 = *(const float4*)(qn_s + (r4 + 0) * FEAT + 4 * jg);
      const float4 q1 = *(const float4*)(qn_s + (r4 + 1) * FEAT + 4 * jg);
      const float4 q2 = *(const float4*)(qn_s + (r4 + 2) * FEAT + 4 * jg);
      const float4 q3 = *(const float4*)(qn_s + (r4 + 3) * FEAT + 4 * jg);
#pragma unroll
      for (int ti = 0; ti < 15; ++ti) {
        const float4 w4 = *(const float4*)(w_s + (tg * 15 + ti) * WST + r4);
        av[ti][0] = fmaf(w4.x, q0.x, fmaf(w4.y, q1.x, fmaf(w4.z, q2.x, fmaf(w4.w, q3.x, av[ti][0]))));
        av[ti][1] = fmaf(w4.x, q0.y, fmaf(w4.y, q1.y, fmaf(w4.z, q2.y, fmaf(w4.w, q3.y, av[ti][1]))));
        av[ti][2] = fmaf(w4.x, q0.z, fmaf(w4.y, q1.z, fmaf(w4.z, q2.z, fmaf(w4.w, q3.z, av[ti][2]))));
        av[ti][3] = fmaf(w4.x, q0.w, fmaf(w4.y, q1.w, fmaf(w4.z, q2.w, fmaf(w4.w, q3.w, av[ti][3]))));
      }
    }
    __syncthreads();
  }

  float* accg = ws + ACC_O;
#pragma unroll
  for (int ti = 0; ti < 15; ++ti) {
#pragma unroll
    for (int c = 0; c < 4; ++c)
      atomicAdd(accg + (tg * 15 + ti) * FEAT + 4 * jg + c, av[ti][c]);
  }
  if (sact) atomicAdd(ws + WSUM_O + lane, wloc);
}

// ---------------- refinement MLP layer 1 ----------------
__global__ __launch_bounds__(256) void k_ref1(
    const float* __restrict__ w1, const float* __restrict__ b1v, float* __restrict__ ws, int step)
{
  const int t = blockIdx.x * 256 + threadIdx.x;
  const int k = t >> 9;
  const int o = t & 511;
  const float rws = 1.0f / fmaxf(ws[WSUM_O + step * NCLS + k], 1e-6f);
  const float* rf = ws + REF_O + k * FEAT;
  const float* ac = ws + ACC_O + (step * NCLS + k) * FEAT;
  float a0 = 0, a1 = 0, a2 = 0, a3 = 0;
  for (int j = 0; j < FEAT; j += 4) {
    a0 = fmaf(rf[j + 0], w1[(j + 0) * 512 + o], a0);
    a1 = fmaf(rf[j + 1], w1[(j + 1) * 512 + o], a1);
    a2 = fmaf(rf[j + 2], w1[(j + 2) * 512 + o], a2);
    a3 = fmaf(rf[j + 3], w1[(j + 3) * 512 + o], a3);
  }
  float c0 = 0, c1 = 0, c2 = 0, c3 = 0;
  for (int j = 0; j < FEAT; j += 4) {
    c0 = fmaf(ac[j + 0], w1[(FEAT + j + 0) * 512 + o], c0);
    c1 = fmaf(ac[j + 1], w1[(FEAT + j + 1) * 512 + o], c1);
    c2 = fmaf(ac[j + 2], w1[(FEAT + j + 2) * 512 + o], c2);
    c3 = fmaf(ac[j + 3], w1[(FEAT + j + 3) * 512 + o], c3);
  }
  float acc = fmaf((c0 + c1) + (c2 + c3), rws, ((a0 + a1) + (a2 + a3)) + b1v[o]);
  ws[HBUF_O + k * FEAT + o] = fmaxf(acc, 0.0f);
}

// ---------------- refinement MLP layer 2 (+residual) ----------------
__global__ __launch_bounds__(256) void k_ref2(
    const float* __restrict__ w2, const float* __restrict__ b2v, float* __restrict__ ws)
{
  const int t = blockIdx.x * 256 + threadIdx.x;
  const int k = t >> 9;
  const int o = t & 511;
  const float* h = ws + HBUF_O + k * FEAT;
  float a0 = 0, a1 = 0, a2 = 0, a3 = 0;
  for (int j = 0; j < 512; j += 4) {
    a0 = fmaf(h[j + 0], w2[(j + 0) * 512 + o], a0);
    a1 = fmaf(h[j + 1], w2[(j + 1) * 512 + o], a1);
    a2 = fmaf(h[j + 2], w2[(j + 2) * 512 + o], a2);
    a3 = fmaf(h[j + 3], w2[(j + 3) * 512 + o], a3);
  }
  ws[REF_O + k * FEAT + o] += 0.1f * (((a0 + a1) + (a2 + a3)) + b2v[o]);
}

// ---------------- pass 2: final logits ----------------
__global__ __launch_bounds__(256, 3) void k_pass2(
    const float* __restrict__ qry, const float* __restrict__ gp, const float* __restrict__ bp,
    const float* __restrict__ ws, const float* __restrict__ tempp, float* __restrict__ out)
{
  __shared__ __align__(16) float rf_s[NCLS * FEAT];
  const int tid = threadIdx.x;
  const int lane = tid & 63;
  const int wv = tid >> 6;

  for (int i = tid; i < NCLS * FEAT / 4; i += 256)
    ((float4*)rf_s)[i] = ((const float4*)(ws + RFLN_O))[i];

  const float4 g0 = ((const float4*)gp)[lane];
  const float4 g1 = ((const float4*)gp)[64 + lane];
  const float4 b0 = ((const float4*)bp)[lane];
  const float4 b1 = ((const float4*)bp)[64 + lane];
  float rsq[NCLS];
#pragma unroll
  for (int k = 0; k < NCLS; ++k) rsq[k] = ws[RSQ_O + k];
  const float tempv = tempp[0];
  __syncthreads();

  const int gw = blockIdx.x * 4 + wv;
  const int NW = gridDim.x * 4;
  for (int p = gw; p < NQ / 2; p += NW) {
    const size_t row = (size_t)p * 2;
    const float4* ra = (const float4*)(qry + row * FEAT);
    const float4* rb = (const float4*)(qry + (row + 1) * FEAT);
    float4 xa0 = ra[lane], xa1 = ra[64 + lane];
    float4 xb0 = rb[lane], xb1 = rb[64 + lane];
    float4 na0, na1, nb0, nb1;
    float qsa, qsb;
    ln_row(xa0, xa1, g0, g1, b0, b1, na0, na1, qsa);
    ln_row(xb0, xb1, g0, g1, b0, b1, nb0, nb1, qsb);
    float da[20], db[20];
#pragma unroll
    for (int k = 0; k < 20; ++k) {
      const float4 p0 = *(const float4*)(rf_s + k * FEAT + 4 * lane);
      const float4 p1 = *(const float4*)(rf_s + k * FEAT + 256 + 4 * lane);
      da[k] = dot8(na0, na1, p0, p1);
      db[k] = dot8(nb0, nb1, p0, p1);
    }
#pragma unroll
    for (int k = 0; k < 20; ++k) { da[k] = allsum(da[k]); db[k] = allsum(db[k]); }
#pragma unroll
    for (int k = 0; k < 20; ++k) {
      da[k] = -fmaxf(fmaf(-2.0f, da[k], qsa + rsq[k]), 0.0f) * tempv;
      db[k] = -fmaxf(fmaf(-2.0f, db[k], qsb + rsq[k]), 0.0f) * tempv;
    }
    float oa = da[0], ob = db[0];
#pragma unroll
    for (int k = 1; k < 20; ++k) {
      oa = (lane == k) ? da[k] : oa;
      ob = (lane == k) ? db[k] : ob;
    }
    if (lane < 20) {
      out[row * 20 + lane] = oa;
      out[(row + 1) * 20 + lane] = ob;
    }
  }
}

extern "C" void kernel_launch(void* const* d_in, const int* in_sizes, int n_in,
                              void* d_out, int out_size, void* d_ws, size_t ws_size,
                              hipStream_t stream) {
  const float* sup   = (const float*)d_in[0];
  const int*   lab   = (const int*)d_in[1];
  const float* qry   = (const float*)d_in[2];
  const float* g     = (const float*)d_in[3];
  const float* b     = (const float*)d_in[4];
  const float* pw1   = (const float*)d_in[5];
  const float* pb1   = (const float*)d_in[6];
  const float* pw2   = (const float*)d_in[7];
  const float* pb2   = (const float*)d_in[8];
  const float* rw1   = (const float*)d_in[9];
  const float* rb1   = (const float*)d_in[10];
  const float* rw2   = (const float*)d_in[11];
  const float* rb2   = (const float*)d_in[12];
  const float* dtemp = (const float*)d_in[13];
  float* ws  = (float*)d_ws;
  float* out = (float*)d_out;

  hipMemsetAsync(ws, 0, (size_t)ZERO_N * sizeof(float), stream);
  k_setup_a<<<25, 512, 0, stream>>>(sup, lab, g, b, ws);
  k_setup_b<<<NCLS, 256, 0, stream>>>(pw1, pb1, ws);
  k_setup_c<<<NCLS, 512, 0, stream>>>(pw2, pb2, ws);
  k_ln20<<<1, 512, 0, stream>>>(g, b, ws, PRAW_O, PROT_O, REF_O, PSQ_O);
  k_pass1<<<256, 512, 0, stream>>>(qry, g, b, ws);
  for (int s = 0; s < 3; ++s) {
    k_ref1<<<40, 256, 0, stream>>>(rw1, rb1, ws, s);
    k_ref2<<<40, 256, 0, stream>>>(rw2, rb2, ws);
  }
  k_ln20<<<1, 512, 0, stream>>>(g, b, ws, REF_O, RFLN_O, -1, RSQ_O);
  k_pass2<<<768, 256, 0, stream>>>(qry, g, b, ws, dtemp, out);
}

// Round 5
// 1208.814 us; speedup vs baseline: 1.7255x; 1.7255x over previous
//
#include <hip/hip_runtime.h>

#define FEAT 512
#define NCLS 20
#define NSUP 200
#define NQ   200000
#define HID  256
#define RB   32     // query rows per block batch in pass1
#define WST  36     // padded stride (floats) for softmax-weight LDS rows

// ---- workspace layout (float offsets) ----
#define ACC_O   0        // 3*20*512 soft^T @ qn accumulators
#define WSUM_O  30720    // 3*20
#define CNT_O   30780    // 20
#define CSUM_O  30800    // 20*512 class sums of LN'd support
#define ZERO_N  41040    // everything before here is zeroed each launch
#define PROT_O  41040    // 20*512 LN'd prototypes
#define PSQ_O   51280    // 20
#define H1_O    51300    // 20*256 proto-MLP hidden
#define PRAW_O  56420    // 20*512 raw prototypes
#define HBUF_O  66660    // 20*512 refine hidden
#define REF_O   76900    // 20*512 refined
#define RFLN_O  87140    // 20*512 LN'd refined
#define RSQ_O   97380    // 20
// new: bf16 query cache for pass2
#define QSQ_O   97408                 // NQ floats: ||qn||^2 per row
#define PROTB_O (QSQ_O + NQ)          // 32 rows x 520 bf16 (padded), zero rows 20..31 = 8320 floats
#define QNB_O   (PROTB_O + 8320)      // NQ*512 bf16 = NQ*256 floats
#define QNB_END (QNB_O + NQ * 256)

typedef __attribute__((ext_vector_type(8))) short bf16x8;
typedef __attribute__((ext_vector_type(4))) float f32x4;

template<int CTRL>
static __device__ __forceinline__ float dpp_add(float v) {
  int r = __builtin_amdgcn_update_dpp(0, __float_as_int(v), CTRL, 0xF, 0xF, true);
  return v + __int_as_float(r);
}

// butterfly sum over all 64 lanes, result in every lane
static __device__ __forceinline__ float allsum(float v) {
  v = dpp_add<0xB1>(v);    // quad_perm [1,0,3,2]  : xor 1
  v = dpp_add<0x4E>(v);    // quad_perm [2,3,0,1]  : xor 2
  v = dpp_add<0x141>(v);   // row_half_mirror      : combine quads within 8
  v = dpp_add<0x140>(v);   // row_mirror           : combine 8s within 16
  v += __int_as_float(__builtin_amdgcn_ds_swizzle(__float_as_int(v), 0x401F)); // xor 16
  v += __shfl_xor(v, 32, 64);                                                  // xor 32
  return v;
}

static __device__ __forceinline__ float dot8(const float4 a0, const float4 a1,
                                             const float4 b0, const float4 b1) {
  float t = a0.x * b0.x;
  t = fmaf(a0.y, b0.y, t); t = fmaf(a0.z, b0.z, t); t = fmaf(a0.w, b0.w, t);
  t = fmaf(a1.x, b1.x, t); t = fmaf(a1.y, b1.y, t); t = fmaf(a1.z, b1.z, t);
  t = fmaf(a1.w, b1.w, t);
  return t;
}

static __device__ __forceinline__ unsigned short f2bf(float f) {
  unsigned u = __float_as_uint(f);
  u += 0x7FFFu + ((u >> 16) & 1u);     // round-to-nearest-even
  return (unsigned short)(u >> 16);
}
static __device__ __forceinline__ ushort4 pack4(float4 v) {
  return make_ushort4(f2bf(v.x), f2bf(v.y), f2bf(v.z), f2bf(v.w));
}

// LayerNorm of one 512-wide row held wave-wide: lane i owns cols [4i,4i+4) and [256+4i, 256+4i+4)
static __device__ __forceinline__ void ln_row(const float4 x0, const float4 x1,
    const float4 g0, const float4 g1, const float4 b0, const float4 b1,
    float4& n0, float4& n1, float& qsq)
{
  float s8 = ((x0.x + x0.y) + (x0.z + x0.w)) + ((x1.x + x1.y) + (x1.z + x1.w));
  float q8 = x0.x * x0.x;
  q8 = fmaf(x0.y, x0.y, q8); q8 = fmaf(x0.z, x0.z, q8); q8 = fmaf(x0.w, x0.w, q8);
  q8 = fmaf(x1.x, x1.x, q8); q8 = fmaf(x1.y, x1.y, q8); q8 = fmaf(x1.z, x1.z, q8);
  q8 = fmaf(x1.w, x1.w, q8);
  float S = allsum(s8);
  float Q = allsum(q8);
  float m = S * (1.0f / FEAT);
  float var = fmaxf(Q * (1.0f / FEAT) - m * m, 0.0f);
  float rs = rsqrtf(var + 1e-5f);
  n0.x = fmaf((x0.x - m) * rs, g0.x, b0.x);
  n0.y = fmaf((x0.y - m) * rs, g0.y, b0.y);
  n0.z = fmaf((x0.z - m) * rs, g0.z, b0.z);
  n0.w = fmaf((x0.w - m) * rs, g0.w, b0.w);
  n1.x = fmaf((x1.x - m) * rs, g1.x, b1.x);
  n1.y = fmaf((x1.y - m) * rs, g1.y, b1.y);
  n1.z = fmaf((x1.z - m) * rs, g1.z, b1.z);
  n1.w = fmaf((x1.w - m) * rs, g1.w, b1.w);
  qsq = allsum(dot8(n0, n1, n0, n1));
}

// ---------------- setup: LN support rows + per-class sums ----------------
__global__ __launch_bounds__(512) void k_setup_a(
    const float* __restrict__ sup, const int* __restrict__ lab,
    const float* __restrict__ gp, const float* __restrict__ bp, float* __restrict__ ws)
{
  const int lane = threadIdx.x & 63;
  const int wv = threadIdx.x >> 6;
  const int row = blockIdx.x * 8 + wv;
  if (row >= NSUP) return;
  const float4 g0 = ((const float4*)gp)[lane];
  const float4 g1 = ((const float4*)gp)[64 + lane];
  const float4 b0 = ((const float4*)bp)[lane];
  const float4 b1 = ((const float4*)bp)[64 + lane];
  const float4* r4 = (const float4*)(sup + (size_t)row * FEAT);
  float4 x0 = r4[lane], x1 = r4[64 + lane];
  float4 n0, n1; float qs;
  ln_row(x0, x1, g0, g1, b0, b1, n0, n1, qs);
  const int c = lab[row];
  float* dst = ws + CSUM_O + c * FEAT + 4 * lane;
  atomicAdd(dst + 0, n0.x); atomicAdd(dst + 1, n0.y);
  atomicAdd(dst + 2, n0.z); atomicAdd(dst + 3, n0.w);
  float* dst2 = dst + 256;
  atomicAdd(dst2 + 0, n1.x); atomicAdd(dst2 + 1, n1.y);
  atomicAdd(dst2 + 2, n1.z); atomicAdd(dst2 + 3, n1.w);
  if (lane == 0) atomicAdd(ws + CNT_O + c, 1.0f);
}

// ---------------- proto MLP layer 1 (relu(cmean@W1+b1)) ----------------
__global__ __launch_bounds__(256) void k_setup_b(
    const float* __restrict__ w1, const float* __restrict__ b1v, float* __restrict__ ws)
{
  const int k = blockIdx.x;
  const int o = threadIdx.x;
  const float rw = 1.0f / fmaxf(ws[CNT_O + k], 1.0f);
  const float* cs = ws + CSUM_O + k * FEAT;
  float a0 = 0, a1 = 0, a2 = 0, a3 = 0;
  for (int j = 0; j < FEAT; j += 4) {
    a0 = fmaf(cs[j + 0], w1[(j + 0) * HID + o], a0);
    a1 = fmaf(cs[j + 1], w1[(j + 1) * HID + o], a1);
    a2 = fmaf(cs[j + 2], w1[(j + 2) * HID + o], a2);
    a3 = fmaf(cs[j + 3], w1[(j + 3) * HID + o], a3);
  }
  float acc = fmaf((a0 + a1) + (a2 + a3), rw, b1v[o]);
  ws[H1_O + k * HID + o] = fmaxf(acc, 0.0f);
}

// ---------------- proto MLP layer 2 ----------------
__global__ __launch_bounds__(512) void k_setup_c(
    const float* __restrict__ w2, const float* __restrict__ b2v, float* __restrict__ ws)
{
  const int k = blockIdx.x;
  const int o = threadIdx.x;
  const float* h = ws + H1_O + k * HID;
  float a0 = 0, a1 = 0, a2 = 0, a3 = 0;
  for (int j = 0; j < HID; j += 4) {
    a0 = fmaf(h[j + 0], w2[(j + 0) * FEAT + o], a0);
    a1 = fmaf(h[j + 1], w2[(j + 1) * FEAT + o], a1);
    a2 = fmaf(h[j + 2], w2[(j + 2) * FEAT + o], a2);
    a3 = fmaf(h[j + 3], w2[(j + 3) * FEAT + o], a3);
  }
  ws[PRAW_O + k * FEAT + o] = ((a0 + a1) + (a2 + a3)) + b2v[o];
}

// ------- LN of the 20 rows at src_o -> dst_o (+optional copy, +sumsq, +optional bf16 padded copy) -------
__global__ __launch_bounds__(512) void k_ln20(
    const float* __restrict__ gp, const float* __restrict__ bp, float* __restrict__ ws,
    int src_o, int dst_o, int dst2_o, int sq_o, int pb_o)
{
  const int lane = threadIdx.x & 63;
  const int wv = threadIdx.x >> 6;
  if (pb_o >= 0) {
    // zero-fill padded bf16 proto block: 32 rows x 520 bf16 = 8320 floats
    for (int i = threadIdx.x; i < 8320; i += 512) ws[pb_o + i] = 0.0f;
    __syncthreads();
  }
  const float4 g0 = ((const float4*)gp)[lane];
  const float4 g1 = ((const float4*)gp)[64 + lane];
  const float4 b0 = ((const float4*)bp)[lane];
  const float4 b1 = ((const float4*)bp)[64 + lane];
  for (int k = wv; k < NCLS; k += 8) {
    const float4* r4 = (const float4*)(ws + src_o + k * FEAT);
    float4 x0 = r4[lane], x1 = r4[64 + lane];
    float4 n0, n1; float qs;
    ln_row(x0, x1, g0, g1, b0, b1, n0, n1, qs);
    float4* d4 = (float4*)(ws + dst_o + k * FEAT);
    d4[lane] = n0; d4[64 + lane] = n1;
    if (dst2_o >= 0) {
      float4* e4 = (float4*)(ws + dst2_o + k * FEAT);
      e4[lane] = n0; e4[64 + lane] = n1;
    }
    if (pb_o >= 0) {
      unsigned short* pr = (unsigned short*)(ws + pb_o) + k * 520;
      *(ushort4*)(pr + 4 * lane) = pack4(n0);
      *(ushort4*)(pr + 256 + 4 * lane) = pack4(n1);
    }
    if (lane == 0) ws[sq_o + k] = qs;
  }
}

// ---------------- pass 1: fused LN + dist + 3 softmaxes + soft^T@qn accumulation ----------------
__global__ __launch_bounds__(512, 2) void k_pass1(
    const float* __restrict__ qry, const float* __restrict__ gp, const float* __restrict__ bp,
    float* __restrict__ ws, unsigned short* __restrict__ qnb, float* __restrict__ qsqg, int doq)
{
  __shared__ __align__(16) float pro_s[NCLS * FEAT];   // 40 KB
  __shared__ __align__(16) float qn_s[RB * FEAT];      // 64 KB
  __shared__ __align__(16) float w_s[60 * WST];        // 8.6 KB

  const int tid = threadIdx.x;
  const int lane = tid & 63;
  const int wv = tid >> 6;

  for (int i = tid; i < NCLS * FEAT / 4; i += 512)
    ((float4*)pro_s)[i] = ((const float4*)(ws + PROT_O))[i];

  const float4 g0 = ((const float4*)gp)[lane];
  const float4 g1 = ((const float4*)gp)[64 + lane];
  const float4 b0 = ((const float4*)bp)[lane];
  const float4 b1 = ((const float4*)bp)[64 + lane];

  float psq[NCLS];
#pragma unroll
  for (int k = 0; k < NCLS; ++k) psq[k] = ws[PSQ_O + k];

  const int myk = lane % 20;
  const int myt = lane / 20;
  const bool sact = lane < 60;
  const float invt = (myt == 0) ? 1.0f : ((myt == 1) ? 0.5f : (1.0f / 3.0f));
  float wloc = 0.0f;

  const int tg = tid >> 7;     // tk group: owns tk = tg*15 .. tg*15+14
  const int jg = tid & 127;    // owns cols 4*jg .. 4*jg+3
  float av[15][4];
#pragma unroll
  for (int a = 0; a < 15; ++a)
#pragma unroll
    for (int c = 0; c < 4; ++c) av[a][c] = 0.0f;

  auto softmax_row = [&](float qs, const float (&d)[20], int lr) {
    float dd[20];
#pragma unroll
    for (int k = 0; k < 20; ++k) dd[k] = fmaxf(fmaf(-2.0f, d[k], qs + psq[k]), 0.0f);
    float mm[10];
#pragma unroll
    for (int k = 0; k < 10; ++k) mm[k] = fminf(dd[k], dd[k + 10]);
#pragma unroll
    for (int k = 0; k < 5; ++k) mm[k] = fminf(mm[k], mm[k + 5]);
    mm[0] = fminf(mm[0], mm[3]);
    mm[1] = fminf(mm[1], mm[4]);
    mm[0] = fminf(mm[0], mm[2]);
    float dmin = fminf(mm[0], mm[1]);
    float dk = dd[0];
#pragma unroll
    for (int k = 1; k < 20; ++k) dk = (myk == k) ? dd[k] : dk;
    float e = __expf((dmin - dk) * invt);
    e = sact ? e : 0.0f;
    float s = e;
    { float t = __shfl_down(s, 16, 64); s += (myk + 16 < 20) ? t : 0.0f; }
    { float t = __shfl_down(s, 8, 64);  s += (myk + 8  < 20) ? t : 0.0f; }
    { float t = __shfl_down(s, 4, 64);  s += (myk + 4  < 20) ? t : 0.0f; }
    { float t = __shfl_down(s, 2, 64);  s += (myk + 2  < 20) ? t : 0.0f; }
    { float t = __shfl_down(s, 1, 64);  s += (myk + 1  < 20) ? t : 0.0f; }
    float denom = __shfl(s, myt * 20, 64);   // group leader has full sum (>=1, safe)
    float wgt = e * __builtin_amdgcn_rcpf(denom);
    if (sact) { w_s[lane * WST + lr] = wgt; wloc += wgt; }
  };

  __syncthreads();

  for (int bt = blockIdx.x; bt < NQ / RB; bt += gridDim.x) {
    const int lr0 = wv * 4;                           // this wave's 4 local rows
    const float* qb = qry + (size_t)(bt * RB + lr0) * FEAT;
    float4 x[4][2];
#pragma unroll
    for (int r = 0; r < 4; ++r) {
      x[r][0] = ((const float4*)(qb + r * FEAT))[lane];
      x[r][1] = ((const float4*)(qb + r * FEAT))[64 + lane];
    }
#pragma unroll
    for (int pr = 0; pr < 2; ++pr) {
      float4 na0, na1, nb0, nb1;
      float qsa, qsb;
      ln_row(x[2 * pr][0], x[2 * pr][1], g0, g1, b0, b1, na0, na1, qsa);
      ln_row(x[2 * pr + 1][0], x[2 * pr + 1][1], g0, g1, b0, b1, nb0, nb1, qsb);
      const int growa = bt * RB + lr0 + 2 * pr;
      if (doq) {
        unsigned short* qa = qnb + (size_t)growa * FEAT;
        *(ushort4*)(qa + 4 * lane) = pack4(na0);
        *(ushort4*)(qa + 256 + 4 * lane) = pack4(na1);
        unsigned short* qbp = qa + FEAT;
        *(ushort4*)(qbp + 4 * lane) = pack4(nb0);
        *(ushort4*)(qbp + 256 + 4 * lane) = pack4(nb1);
        if (lane == 0) { qsqg[growa] = qsa; qsqg[growa + 1] = qsb; }
      }
      float4* qa4 = (float4*)(qn_s + (lr0 + 2 * pr) * FEAT);
      qa4[lane] = na0; qa4[64 + lane] = na1;
      float4* qb4 = (float4*)(qn_s + (lr0 + 2 * pr + 1) * FEAT);
      qb4[lane] = nb0; qb4[64 + lane] = nb1;
      float da[20], db[20];
#pragma unroll
      for (int k = 0; k < 20; ++k) {
        const float4 p0 = *(const float4*)(pro_s + k * FEAT + 4 * lane);
        const float4 p1 = *(const float4*)(pro_s + k * FEAT + 256 + 4 * lane);
        da[k] = dot8(na0, na1, p0, p1);
        db[k] = dot8(nb0, nb1, p0, p1);
      }
#pragma unroll
      for (int k = 0; k < 20; ++k) { da[k] = allsum(da[k]); db[k] = allsum(db[k]); }
      softmax_row(qsa, da, lr0 + 2 * pr);
      softmax_row(qsb, db, lr0 + 2 * pr + 1);
    }
    __syncthreads();
    // phase B: rank-32 update, thread owns (15 tk) x (4 cols) in registers
    for (int r4 = 0; r4 < RB; r4 += 4) {
      const float4 q0 = *(const float4*)(qn_s + (r4 + 0) * FEAT + 4 * jg);
      const float4 q1 = *(const float4*)(qn_s + (r4 + 1) * FEAT + 4 * jg);
      const float4 q2 = *(const float4*)(qn_s + (r4 + 2) * FEAT + 4 * jg);
      const float4 q3 = *(const float4*)(qn_s + (r4 + 3) * FEAT + 4 * jg);
#pragma unroll
      for (int ti = 0; ti < 15; ++ti) {
        const float4 w4 = *(const float4*)(w_s + (tg * 15 + ti) * WST + r4);
        av[ti][0] = fmaf(w4.x, q0.x, fmaf(w4.y, q1.x, fmaf(w4.z, q2.x, fmaf(w4.w, q3.x, av[ti][0]))));
        av[ti][1] = fmaf(w4.x, q0.y, fmaf(w4.y, q1.y, fmaf(w4.z, q2.y, fmaf(w4.w, q3.y, av[ti][1]))));
        av[ti][2] = fmaf(w4.x, q0.z, fmaf(w4.y, q1.z, fmaf(w4.z, q2.z, fmaf(w4.w, q3.z, av[ti][2]))));
        av[ti][3] = fmaf(w4.x, q0.w, fmaf(w4.y, q1.w, fmaf(w4.z, q2.w, fmaf(w4.w, q3.w, av[ti][3]))));
      }
    }
    __syncthreads();
  }

  float* accg = ws + ACC_O;
#pragma unroll
  for (int ti = 0; ti < 15; ++ti) {
#pragma unroll
    for (int c = 0; c < 4; ++c)
      atomicAdd(accg + (tg * 15 + ti) * FEAT + 4 * jg + c, av[ti][c]);
  }
  if (sact) atomicAdd(ws + WSUM_O + lane, wloc);
}

// ---------------- refinement MLP layer 1 ----------------
__global__ __launch_bounds__(256) void k_ref1(
    const float* __restrict__ w1, const float* __restrict__ b1v, float* __restrict__ ws, int step)
{
  const int t = blockIdx.x * 256 + threadIdx.x;
  const int k = t >> 9;
  const int o = t & 511;
  const float rws = 1.0f / fmaxf(ws[WSUM_O + step * NCLS + k], 1e-6f);
  const float* rf = ws + REF_O + k * FEAT;
  const float* ac = ws + ACC_O + (step * NCLS + k) * FEAT;
  float a0 = 0, a1 = 0, a2 = 0, a3 = 0;
  for (int j = 0; j < FEAT; j += 4) {
    a0 = fmaf(rf[j + 0], w1[(j + 0) * 512 + o], a0);
    a1 = fmaf(rf[j + 1], w1[(j + 1) * 512 + o], a1);
    a2 = fmaf(rf[j + 2], w1[(j + 2) * 512 + o], a2);
    a3 = fmaf(rf[j + 3], w1[(j + 3) * 512 + o], a3);
  }
  float c0 = 0, c1 = 0, c2 = 0, c3 = 0;
  for (int j = 0; j < FEAT; j += 4) {
    c0 = fmaf(ac[j + 0], w1[(FEAT + j + 0) * 512 + o], c0);
    c1 = fmaf(ac[j + 1], w1[(FEAT + j + 1) * 512 + o], c1);
    c2 = fmaf(ac[j + 2], w1[(FEAT + j + 2) * 512 + o], c2);
    c3 = fmaf(ac[j + 3], w1[(FEAT + j + 3) * 512 + o], c3);
  }
  float acc = fmaf((c0 + c1) + (c2 + c3), rws, ((a0 + a1) + (a2 + a3)) + b1v[o]);
  ws[HBUF_O + k * FEAT + o] = fmaxf(acc, 0.0f);
}

// ---------------- refinement MLP layer 2 (+residual) ----------------
__global__ __launch_bounds__(256) void k_ref2(
    const float* __restrict__ w2, const float* __restrict__ b2v, float* __restrict__ ws)
{
  const int t = blockIdx.x * 256 + threadIdx.x;
  const int k = t >> 9;
  const int o = t & 511;
  const float* h = ws + HBUF_O + k * FEAT;
  float a0 = 0, a1 = 0, a2 = 0, a3 = 0;
  for (int j = 0; j < 512; j += 4) {
    a0 = fmaf(h[j + 0], w2[(j + 0) * 512 + o], a0);
    a1 = fmaf(h[j + 1], w2[(j + 1) * 512 + o], a1);
    a2 = fmaf(h[j + 2], w2[(j + 2) * 512 + o], a2);
    a3 = fmaf(h[j + 3], w2[(j + 3) * 512 + o], a3);
  }
  ws[REF_O + k * FEAT + o] += 0.1f * (((a0 + a1) + (a2 + a3)) + b2v[o]);
}

// ---------------- pass 2 (MFMA): logits from cached bf16 qn ----------------
__global__ __launch_bounds__(256) void k_pass2_mfma(
    const unsigned short* __restrict__ qnb, const float* __restrict__ qsqg,
    const float* __restrict__ ws, const float* __restrict__ tempp, float* __restrict__ out)
{
  __shared__ __align__(16) unsigned char pb_s[32 * 1040];  // padded bf16 protos, 33280 B
  __shared__ __align__(16) float lg_s[64 * 20];            // logits stage, 5120 B

  const int tid = threadIdx.x;
  const int lane = tid & 63;
  const int wv = tid >> 6;
  const int r0 = blockIdx.x * 64;

  {
    const float4* src = (const float4*)(ws + PROTB_O);
    float4* dst = (float4*)pb_s;
    for (int i = tid; i < 2080; i += 256) dst[i] = src[i];
  }
  const float tempv = tempp[0];
  const int col0 = lane & 15;
  const float rsq0 = ws[RSQ_O + col0];
  const float rsq1 = (col0 < 4) ? ws[RSQ_O + 16 + col0] : 0.0f;
  const int rbase = r0 + wv * 16 + (lane >> 4) * 4;
  const float qs0 = qsqg[rbase + 0], qs1 = qsqg[rbase + 1];
  const float qs2 = qsqg[rbase + 2], qs3 = qsqg[rbase + 3];
  __syncthreads();

  f32x4 acc0 = {0.f, 0.f, 0.f, 0.f}, acc1 = {0.f, 0.f, 0.f, 0.f};
  const int arow = r0 + wv * 16 + (lane & 15);
  const unsigned short* aptr = qnb + (size_t)arow * FEAT + (lane >> 4) * 8;
  const unsigned char* b0p = pb_s + (size_t)(lane & 15) * 1040 + (lane >> 4) * 16;
  const unsigned char* b1p = b0p + 16 * 1040;
#pragma unroll 4
  for (int kk = 0; kk < 16; ++kk) {
    bf16x8 a  = *(const bf16x8*)(aptr + kk * 32);
    bf16x8 bb0 = *(const bf16x8*)(b0p + kk * 64);
    bf16x8 bb1 = *(const bf16x8*)(b1p + kk * 64);
    acc0 = __builtin_amdgcn_mfma_f32_16x16x32_bf16(a, bb0, acc0, 0, 0, 0);
    acc1 = __builtin_amdgcn_mfma_f32_16x16x32_bf16(a, bb1, acc1, 0, 0, 0);
  }

  // epilogue: logit = -max(qsq + rsq - 2*qp, 0) * temp
  {
    const int lrow = wv * 16 + (lane >> 4) * 4;
    float qsv[4] = {qs0, qs1, qs2, qs3};
#pragma unroll
    for (int r = 0; r < 4; ++r) {
      float v0 = -fmaxf(qsv[r] + rsq0 - 2.0f * acc0[r], 0.0f) * tempv;
      lg_s[(lrow + r) * 20 + col0] = v0;
      if (col0 < 4) {
        float v1 = -fmaxf(qsv[r] + rsq1 - 2.0f * acc1[r], 0.0f) * tempv;
        lg_s[(lrow + r) * 20 + 16 + col0] = v1;
      }
    }
  }
  __syncthreads();
  const float4* ls4 = (const float4*)lg_s;
  float4* o4 = (float4*)(out + (size_t)r0 * 20);
  for (int i = tid; i < 320; i += 256) o4[i] = ls4[i];
}

// ---------------- pass 2 legacy (fallback when ws is small) ----------------
__global__ __launch_bounds__(256, 3) void k_pass2(
    const float* __restrict__ qry, const float* __restrict__ gp, const float* __restrict__ bp,
    const float* __restrict__ ws, const float* __restrict__ tempp, float* __restrict__ out)
{
  __shared__ __align__(16) float rf_s[NCLS * FEAT];
  const int tid = threadIdx.x;
  const int lane = tid & 63;
  const int wv = tid >> 6;

  for (int i = tid; i < NCLS * FEAT / 4; i += 256)
    ((float4*)rf_s)[i] = ((const float4*)(ws + RFLN_O))[i];

  const float4 g0 = ((const float4*)gp)[lane];
  const float4 g1 = ((const float4*)gp)[64 + lane];
  const float4 b0 = ((const float4*)bp)[lane];
  const float4 b1 = ((const float4*)bp)[64 + lane];
  float rsq[NCLS];
#pragma unroll
  for (int k = 0; k < NCLS; ++k) rsq[k] = ws[RSQ_O + k];
  const float tempv = tempp[0];
  __syncthreads();

  const int gw = blockIdx.x * 4 + wv;
  const int NW = gridDim.x * 4;
  for (int p = gw; p < NQ / 2; p += NW) {
    const size_t row = (size_t)p * 2;
    const float4* ra = (const float4*)(qry + row * FEAT);
    const float4* rb = (const float4*)(qry + (row + 1) * FEAT);
    float4 xa0 = ra[lane], xa1 = ra[64 + lane];
    float4 xb0 = rb[lane], xb1 = rb[64 + lane];
    float4 na0, na1, nb0, nb1;
    float qsa, qsb;
    ln_row(xa0, xa1, g0, g1, b0, b1, na0, na1, qsa);
    ln_row(xb0, xb1, g0, g1, b0, b1, nb0, nb1, qsb);
    float da[20], db[20];
#pragma unroll
    for (int k = 0; k < 20; ++k) {
      const float4 p0 = *(const float4*)(rf_s + k * FEAT + 4 * lane);
      const float4 p1 = *(const float4*)(rf_s + k * FEAT + 256 + 4 * lane);
      da[k] = dot8(na0, na1, p0, p1);
      db[k] = dot8(nb0, nb1, p0, p1);
    }
#pragma unroll
    for (int k = 0; k < 20; ++k) { da[k] = allsum(da[k]); db[k] = allsum(db[k]); }
#pragma unroll
    for (int k = 0; k < 20; ++k) {
      da[k] = -fmaxf(fmaf(-2.0f, da[k], qsa + rsq[k]), 0.0f) * tempv;
      db[k] = -fmaxf(fmaf(-2.0f, db[k], qsb + rsq[k]), 0.0f) * tempv;
    }
    float oa = da[0], ob = db[0];
#pragma unroll
    for (int k = 1; k < 20; ++k) {
      oa = (lane == k) ? da[k] : oa;
      ob = (lane == k) ? db[k] : ob;
    }
    if (lane < 20) {
      out[row * 20 + lane] = oa;
      out[(row + 1) * 20 + lane] = ob;
    }
  }
}

extern "C" void kernel_launch(void* const* d_in, const int* in_sizes, int n_in,
                              void* d_out, int out_size, void* d_ws, size_t ws_size,
                              hipStream_t stream) {
  const float* sup   = (const float*)d_in[0];
  const int*   lab   = (const int*)d_in[1];
  const float* qry   = (const float*)d_in[2];
  const float* g     = (const float*)d_in[3];
  const float* b     = (const float*)d_in[4];
  const float* pw1   = (const float*)d_in[5];
  const float* pb1   = (const float*)d_in[6];
  const float* pw2   = (const float*)d_in[7];
  const float* pb2   = (const float*)d_in[8];
  const float* rw1   = (const float*)d_in[9];
  const float* rb1   = (const float*)d_in[10];
  const float* rw2   = (const float*)d_in[11];
  const float* rb2   = (const float*)d_in[12];
  const float* dtemp = (const float*)d_in[13];
  float* ws  = (float*)d_ws;
  float* out = (float*)d_out;

  const bool big = ws_size >= (size_t)QNB_END * sizeof(float);

  hipMemsetAsync(ws, 0, (size_t)ZERO_N * sizeof(float), stream);
  k_setup_a<<<25, 512, 0, stream>>>(sup, lab, g, b, ws);
  k_setup_b<<<NCLS, 256, 0, stream>>>(pw1, pb1, ws);
  k_setup_c<<<NCLS, 512, 0, stream>>>(pw2, pb2, ws);
  k_ln20<<<1, 512, 0, stream>>>(g, b, ws, PRAW_O, PROT_O, REF_O, PSQ_O, -1);
  k_pass1<<<256, 512, 0, stream>>>(qry, g, b, ws,
                                   (unsigned short*)(ws + QNB_O), ws + QSQ_O, big ? 1 : 0);
  for (int s = 0; s < 3; ++s) {
    k_ref1<<<40, 256, 0, stream>>>(rw1, rb1, ws, s);
    k_ref2<<<40, 256, 0, stream>>>(rw2, rb2, ws);
  }
  k_ln20<<<1, 512, 0, stream>>>(g, b, ws, REF_O, RFLN_O, -1, RSQ_O, big ? PROTB_O : -1);
  if (big) {
    k_pass2_mfma<<<NQ / 64, 256, 0, stream>>>((const unsigned short*)(ws + QNB_O),
                                              ws + QSQ_O, ws, dtemp, out);
  } else {
    k_pass2<<<768, 256, 0, stream>>>(qry, g, b, ws, dtemp, out);
  }
}